// Round 9
// baseline (1925.017 us; speedup 1.0000x reference)
//
#include <hip/hip_runtime.h>

#define B_ 8
#define N_ 8192
#define S_ 1024
#define NS_ 64

typedef float v2f __attribute__((ext_vector_type(2)));
typedef unsigned long long u64;
typedef unsigned long long u64x2 __attribute__((ext_vector_type(2)));
typedef short bf16x8 __attribute__((ext_vector_type(8)));
typedef float f32x4 __attribute__((ext_vector_type(4)));

// out layout (floats)
#define OUT0 0                 // new_xyz (B,3,1024)
#define OUT1 24576             // new_points (B,128,1024)
#define OUT2 1073152           // new_seed (B,1024); fps int-bits until down_kernel converts

// ---------------------------------------------------------------------------
// DPP 64-lane reductions (row_shr 1/2/4/8, row_bcast 15/31; result lane 63).
// HW-validated on gfx950 in rounds 6-17.
// ---------------------------------------------------------------------------
template <int CTRL>
static __device__ __forceinline__ float dpp_max_step(float v) {
    int o = __builtin_amdgcn_update_dpp(__float_as_int(v), __float_as_int(v),
                                        CTRL, 0xf, 0xf, false);
    return fmaxf(v, __int_as_float(o));
}
static __device__ __forceinline__ float wave_max_f32(float v) {
    v = dpp_max_step<0x111>(v);
    v = dpp_max_step<0x112>(v);
    v = dpp_max_step<0x114>(v);
    v = dpp_max_step<0x118>(v);
    v = dpp_max_step<0x142>(v);
    v = dpp_max_step<0x143>(v);
    return __int_as_float(__builtin_amdgcn_readlane(__float_as_int(v), 63));
}
template <int CTRL>
static __device__ __forceinline__ unsigned dpp_umin_step(unsigned v) {
    unsigned o = (unsigned)__builtin_amdgcn_update_dpp((int)v, (int)v,
                                                       CTRL, 0xf, 0xf, false);
    return v < o ? v : o;
}
static __device__ __forceinline__ unsigned wave_min_u32(unsigned v) {
    v = dpp_umin_step<0x111>(v);
    v = dpp_umin_step<0x112>(v);
    v = dpp_umin_step<0x114>(v);
    v = dpp_umin_step<0x118>(v);
    v = dpp_umin_step<0x142>(v);
    v = dpp_umin_step<0x143>(v);
    return (unsigned)__builtin_amdgcn_readlane((int)v, 63);
}

// round-to-nearest-even f32 -> bf16 bits
static __device__ __forceinline__ short f2bf(float f) {
    unsigned u = __float_as_uint(f);
    return (short)((u + 0x7FFFu + ((u >> 16) & 1u)) >> 16);
}

// ---------------------------------------------------------------------------
// Kernel 1: farthest point sampling — R25 two-batches-per-CU.
// 4 blocks x 512 threads, __launch_bounds__(512,2). Waves 0-3 = batch 2*blk,
// waves 4-7 = batch 2*blk+1; HW places wave w on SIMD w%4, so each SIMD
// hosts one wave of EACH batch. During one batch's serial-chain stalls
// (DPP latency, slot reads, centroid L2 loads, barrier skew) the other
// batch's wave issues — per-step wall goes from issue(940)+stall(~1400) to
// ~2x issue + small residual, for TWO batches at once.
// Per-half body is byte-identical to the verified R24 kernel (tl = t&255):
// J=16 (32 pts/lane), local-max mask + v_max3, f32 wave-max + u32 wave-min,
// per-wave u64 LDS slot + shared lockstep s_barrier + 3-compare max,
// parity-double-buffered slots, seedL in LDS dumped once at the end.
// Negative results (do NOT retry): LDS coord arrays for the inner loop
// (R8/R10); CONCURRENT fps/down fusion (R13/R14); MULTI-CU per-step sync
// via global flags (R19/R20: ~4400 cy/step => 2100 us); intra-block LDS
// tag-spin + fused u64 DPP argmax (R21: +100 us); inline-asm v_pk_* dist
// loop (R22: +154 us); VGPR pinning via empty asm (R24: no-op, VGPR stays
// 84 — compiler keeps cloud in AGPRs regardless).
// ---------------------------------------------------------------------------
#define FPS_T 512
#define FPS_J 16    // v2f per thread (32 points)

__global__ __launch_bounds__(FPS_T, 2) void fps_kernel(const float* __restrict__ xyz,
                                                       float* out) {
    const int blk = blockIdx.x;         // 0..3
    const int t = threadIdx.x;          // 0..511
    const int half = t >> 8;            // 0/1: which batch of the pair
    const int tl = t & 255;             // thread index within the half
    const int lane = t & 63;
    const int wq = tl >> 6;             // wave within half, 0..3
    const int b = (blk << 1) | half;    // batch 0..7
    const float* X = xyz + b * 3 * N_;

    v2f px2[FPS_J], py2[FPS_J], pz2[FPS_J], dist2[FPS_J];
#pragma unroll
    for (int j = 0; j < FPS_J; ++j) {
        int n = tl + 512 * j;           // .x -> n, .y -> n + 256
        px2[j] = (v2f){X[n], X[n + 256]};
        py2[j] = (v2f){X[N_ + n], X[N_ + n + 256]};
        pz2[j] = (v2f){X[2 * N_ + n], X[2 * N_ + n + 256]};
        dist2[j] = (v2f){1e10f, 1e10f};
    }

    __shared__ u64 slots[2][2][4];      // [half][parity][wave]
    __shared__ float seedL[2][S_];

    int ci = 0;
    float c0 = X[0], c1 = X[N_], c2 = X[2 * N_];

    for (int step = 0; step < S_; ++step) {
        if (tl == 0) seedL[half][step] = __int_as_float(ci);

        float mvs = -1.0f;
        {
#pragma clang fp contract(off)
            v2f c0v = (v2f){c0, c0};
            v2f c1v = (v2f){c1, c1};
            v2f c2v = (v2f){c2, c2};
#pragma unroll
            for (int j = 0; j < FPS_J; ++j) {
                v2f e0 = px2[j] - c0v;
                v2f e1 = py2[j] - c1v;
                v2f e2 = pz2[j] - c2v;
                v2f q0 = e0 * e0;
                v2f q1 = e1 * e1;
                v2f q2 = e2 * e2;
                v2f d  = (q0 + q1) + q2;
                v2f dm = __builtin_elementwise_min(dist2[j], d);
                dist2[j] = dm;
                mvs = fmaxf(mvs, fmaxf(dm.x, dm.y));   // v_max3_f32
            }
        }
        float m = mvs;                  // lane-local max of 32 elems

        // mask vs LOCAL max — schedules under the DPP wave-max chain.
        unsigned mask = 0u;
#pragma unroll
        for (int j = 0; j < FPS_J; ++j) {
            if (dist2[j].x == m) mask |= (1u << (2 * j));
            if (dist2[j].y == m) mask |= (1u << (2 * j + 1));
        }
        float wmax = wave_max_f32(m);

        unsigned c = (unsigned)(__ffs(mask) - 1);   // mask != 0 always
        unsigned cand = (m == wmax) ? ((unsigned)tl | (c << 8)) : 0xffffffffu;
        unsigned widx = wave_min_u32(cand);

        if (lane == 63) {
            u64 key = ((u64)__float_as_uint(wmax) << 13) | (u64)(8191u - widx);
            slots[half][step & 1][wq] = key;
        }
        __syncthreads();                // lockstep barrier for both halves

        const u64* sp = slots[half][step & 1];
        u64x2 pA = *(const u64x2*)&sp[0];           // ds_read_b128
        u64x2 pB = *(const u64x2*)&sp[2];           // ds_read_b128
        u64 ka = (pA.x > pA.y) ? pA.x : pA.y;
        u64 kb = (pB.x > pB.y) ? pB.x : pB.y;
        u64 km = (ka > kb) ? ka : kb;
        ci = 8191 - (int)(km & 0x1fffull);

        int cu = __builtin_amdgcn_readfirstlane(ci);
        c0 = X[cu];
        c1 = X[N_ + cu];
        c2 = X[2 * N_ + cu];
    }

    __syncthreads();                    // seedL fully written
    float* oseed = out + OUT2 + b * S_;
#pragma unroll
    for (int k = 0; k < 4; ++k)
        oseed[tl + 256 * k] = seedL[half][tl + 256 * k];
}

// ---------------------------------------------------------------------------
// Kernel 1b: one-shot weight conversion w1 (64x64) + w2 (128x64) -> bf16 in
// d_ws. Shared by all 8192 down_kernel blocks.
// ---------------------------------------------------------------------------
__global__ __launch_bounds__(256) void wconv_kernel(const float* __restrict__ w1,
                                                    const float* __restrict__ w2,
                                                    short* __restrict__ wbf) {
    int t = blockIdx.x * 256 + threadIdx.x;   // 0..12287
    float v = (t < 4096) ? w1[t] : w2[t - 4096];
    wbf[t] = f2bf(v);
}

// ---------------------------------------------------------------------------
// Kernel 2: fused downstream — one block (256 thr, 4 waves) per centroid:
//   (a) read fps idx bits from OUT2 (broadcast), write new_xyz + new_seed
//   (b) 4-wave ball query, FIXED 16-iteration loop
//   (c) MFMA mlp (R16-verified layouts); weights from pre-converted bf16
//       d_ws when available (wbf != nullptr), else inline f2bf fallback.
// ---------------------------------------------------------------------------
__global__ __launch_bounds__(256) void down_kernel(
    const float* __restrict__ xyz, const float* __restrict__ pts,
    const int* __restrict__ seed,
    const float* __restrict__ w0, const float* __restrict__ b0,
    const float* __restrict__ g0, const float* __restrict__ be0,
    const float* __restrict__ m0, const float* __restrict__ v0,
    const float* __restrict__ w1, const float* __restrict__ b1,
    const float* __restrict__ g1, const float* __restrict__ be1,
    const float* __restrict__ m1, const float* __restrict__ v1,
    const float* __restrict__ w2, const float* __restrict__ b2,
    const float* __restrict__ g2, const float* __restrict__ be2,
    const float* __restrict__ m2, const float* __restrict__ v2,
    float* out, const short* __restrict__ wbf) {
    const int sg = blockIdx.x;
    const int b = sg >> 10, s = sg & 1023;
    const int t = threadIdx.x;
    const int lane = t & 63;
    const int wq = __builtin_amdgcn_readfirstlane(t >> 6);   // 0..3
    const int ln = lane & 15;
    const int quad = (lane >> 4) & 3;

    __shared__ float f0[64 * 9];
    __shared__ short featA[64 * 72];
    __shared__ short featB[64 * 72];
    __shared__ float wmaxs[4 * 132];
    __shared__ float scs[256], ofs[256];
    __shared__ int cand[4 * 64];
    __shared__ int cnts[4];
    __shared__ int gis[64];

    const float* X = xyz + b * 3 * N_;

    // (a) broadcast read of fps index; centroid coords
    int ci = __float_as_int(out[OUT2 + sg]) & 8191;
    float cx = X[ci], cy = X[N_ + ci], cz = X[2 * N_ + ci];

    // per-channel BN fold (one sqrt+div per thread)
    {
        float sc, of;
        if (t < 64) {
            int c = t;
            sc = g0[c] / sqrtf(v0[c] + 1e-5f);
            of = (b0[c] - m0[c]) * sc + be0[c];
        } else if (t < 128) {
            int c = t - 64;
            sc = g1[c] / sqrtf(v1[c] + 1e-5f);
            of = (b1[c] - m1[c]) * sc + be1[c];
        } else {
            int c = t - 128;
            sc = g2[c] / sqrtf(v2[c] + 1e-5f);
            of = (b2[c] - m2[c]) * sc + be2[c];
        }
        scs[t] = sc;
        ofs[t] = of;
    }
    __syncthreads();   // all OUT2 reads complete (vmcnt drained) before overwrite

    if (t == 0) {
        out[OUT0 + (b * 3 + 0) * S_ + s] = cx;
        out[OUT0 + (b * 3 + 1) * S_ + s] = cy;
        out[OUT0 + (b * 3 + 2) * S_ + s] = cz;
        out[OUT2 + sg] = (float)seed[b * N_ + ci];
    }

    // (b) 4-wave ball query: wave wq scans [2048*wq, 2048*wq+2048), 16 iters
    {
        int cnt = 0;
        const int wbase = wq << 11;
#pragma unroll 2
        for (int base = 0; base < 2048; base += 128) {
            int n0 = wbase + base + lane;
            int n1 = n0 + 64;
            float x0 = X[n0], y0 = X[N_ + n0], z0 = X[2 * N_ + n0];
            float x1 = X[n1], y1 = X[N_ + n1], z1 = X[2 * N_ + n1];
            float e0 = x0 - cx, e1 = y0 - cy, e2 = z0 - cz;
            float d0 = fmaf(e2, e2, fmaf(e1, e1, e0 * e0));
            float q0 = x1 - cx, q1 = y1 - cy, q2 = z1 - cz;
            float d1 = fmaf(q2, q2, fmaf(q1, q1, q0 * q0));

            u64 mask0 = __ballot(d0 <= 0.04f);
            if (mask0) {
                int pos = cnt + (int)__popcll(mask0 & ((1ull << lane) - 1ull));
                if ((d0 <= 0.04f) && pos < NS_) cand[(wq << 6) + pos] = n0;
                cnt += (int)__popcll(mask0);
            }
            u64 mask1 = __ballot(d1 <= 0.04f);
            if (mask1) {
                int pos = cnt + (int)__popcll(mask1 & ((1ull << lane) - 1ull));
                if ((d1 <= 0.04f) && pos < NS_) cand[(wq << 6) + pos] = n1;
                cnt += (int)__popcll(mask1);
            }
        }
        if (lane == 0) cnts[wq] = cnt;
    }
    __syncthreads();

    // merge: first 64 in global ascending index order; pad with overall-first
    if (t < 64) {
        int k = t;
        int start = 0, sel = -1, firstv = -1;
#pragma unroll
        for (int w = 0; w < 4; ++w) {
            int cw = min(cnts[w], NS_);
            if (firstv < 0 && cw > 0) firstv = cand[(w << 6)];
            if (sel < 0 && k < start + cw) sel = cand[(w << 6) + (k - start)];
            start += cw;
        }
        if (sel < 0) sel = firstv;
        gis[t] = sel;
    }
    __syncthreads();

    if (t < 64) {
        int gidx = gis[t] & 8191;
        const float* P = pts + b * 3 * N_;
        f0[t * 9 + 0] = X[gidx] - cx;
        f0[t * 9 + 1] = X[N_ + gidx] - cy;
        f0[t * 9 + 2] = X[2 * N_ + gidx] - cz;
        f0[t * 9 + 3] = P[gidx];
        f0[t * 9 + 4] = P[N_ + gidx];
        f0[t * 9 + 5] = P[2 * N_ + gidx];
    }
    __syncthreads();

    // (c) layer 0: 6 -> 64 on VALU; point = lane, wave owns 16-channel slice
    {
        float in[6];
#pragma unroll
        for (int c = 0; c < 6; ++c) in[c] = f0[lane * 9 + c];
#pragma unroll 1
        for (int i = 0; i < 16; i += 4) {
            int o = wq * 16 + i;
            float a0 = 0.f, a1 = 0.f, a2 = 0.f, a3 = 0.f;
#pragma unroll
            for (int c = 0; c < 6; ++c) {
                float rc = in[c];
                a0 = fmaf(rc, w0[(o + 0) * 6 + c], a0);
                a1 = fmaf(rc, w0[(o + 1) * 6 + c], a1);
                a2 = fmaf(rc, w0[(o + 2) * 6 + c], a2);
                a3 = fmaf(rc, w0[(o + 3) * 6 + c], a3);
            }
            featA[lane * 72 + o + 0] = f2bf(fmaxf(fmaf(a0, scs[o + 0], ofs[o + 0]), 0.f));
            featA[lane * 72 + o + 1] = f2bf(fmaxf(fmaf(a1, scs[o + 1], ofs[o + 1]), 0.f));
            featA[lane * 72 + o + 2] = f2bf(fmaxf(fmaf(a2, scs[o + 2], ofs[o + 2]), 0.f));
            featA[lane * 72 + o + 3] = f2bf(fmaxf(fmaf(a3, scs[o + 3], ofs[o + 3]), 0.f));
        }
    }
    __syncthreads();

    const int arow = 16 * wq + ln;   // this wave's m-tile row for A-frags
    const bool usebf = (wbf != nullptr);

    // layer 1: 64 -> 64 via MFMA (4 ntiles x 2 ksteps)
    {
        bf16x8 a1f[2];
#pragma unroll
        for (int ks = 0; ks < 2; ++ks)
            a1f[ks] = *(const bf16x8*)&featA[arow * 72 + ks * 32 + quad * 8];

#pragma unroll
        for (int nt = 0; nt < 4; ++nt) {
            f32x4 acc = {0.f, 0.f, 0.f, 0.f};
#pragma unroll
            for (int ks = 0; ks < 2; ++ks) {
                int off = (nt * 16 + ln) * 64 + ks * 32 + quad * 8;
                bf16x8 bf;
                if (usebf) {
                    bf = *(const bf16x8*)&wbf[off];
                } else {
                    const float* wr = w1 + off;
                    float4 p = *(const float4*)wr;
                    float4 q = *(const float4*)(wr + 4);
                    bf = (bf16x8){f2bf(p.x), f2bf(p.y), f2bf(p.z), f2bf(p.w),
                                  f2bf(q.x), f2bf(q.y), f2bf(q.z), f2bf(q.w)};
                }
                acc = __builtin_amdgcn_mfma_f32_16x16x32_bf16(a1f[ks], bf, acc, 0, 0, 0);
            }
            int o = nt * 16 + ln;
            float sc = scs[64 + o], of = ofs[64 + o];
#pragma unroll
            for (int reg = 0; reg < 4; ++reg) {
                float y = fmaxf(fmaf(acc[reg], sc, of), 0.f);
                featB[(16 * wq + quad * 4 + reg) * 72 + o] = f2bf(y);
            }
        }
    }
    // no barrier: each wave reads back only its own m-tile rows

    // layer 2: 64 -> 128 via MFMA (8 ntiles x 2 ksteps) + fused k-max
    {
        bf16x8 a2f[2];
#pragma unroll
        for (int ks = 0; ks < 2; ++ks)
            a2f[ks] = *(const bf16x8*)&featB[arow * 72 + ks * 32 + quad * 8];

#pragma unroll
        for (int nt = 0; nt < 8; ++nt) {
            f32x4 acc = {0.f, 0.f, 0.f, 0.f};
#pragma unroll
            for (int ks = 0; ks < 2; ++ks) {
                int off = (nt * 16 + ln) * 64 + ks * 32 + quad * 8;
                bf16x8 bf;
                if (usebf) {
                    bf = *(const bf16x8*)&wbf[4096 + off];
                } else {
                    const float* wr = w2 + off;
                    float4 p = *(const float4*)wr;
                    float4 q = *(const float4*)(wr + 4);
                    bf = (bf16x8){f2bf(p.x), f2bf(p.y), f2bf(p.z), f2bf(p.w),
                                  f2bf(q.x), f2bf(q.y), f2bf(q.z), f2bf(q.w)};
                }
                acc = __builtin_amdgcn_mfma_f32_16x16x32_bf16(a2f[ks], bf, acc, 0, 0, 0);
            }
            int o = nt * 16 + ln;
            float sc = scs[128 + o], of = ofs[128 + o];
            float m = -1.f;
#pragma unroll
            for (int reg = 0; reg < 4; ++reg) {
                float y = fmaxf(fmaf(acc[reg], sc, of), 0.f);
                m = fmaxf(m, y);
            }
            m = fmaxf(m, __shfl_xor(m, 16, 64));
            m = fmaxf(m, __shfl_xor(m, 32, 64));
            if (lane < 16) wmaxs[wq * 132 + o] = m;
        }
    }
    __syncthreads();

    // final: max over the 4 waves' m-tiles, store new_points
    if (t < 128) {
        float m = fmaxf(fmaxf(wmaxs[0 * 132 + t], wmaxs[1 * 132 + t]),
                        fmaxf(wmaxs[2 * 132 + t], wmaxs[3 * 132 + t]));
        out[OUT1 + (b * 128 + t) * S_ + s] = m;
    }
}

extern "C" void kernel_launch(void* const* d_in, const int* in_sizes, int n_in,
                              void* d_out, int out_size, void* d_ws, size_t ws_size,
                              hipStream_t stream) {
    const float* xyz  = (const float*)d_in[0];
    const float* pts  = (const float*)d_in[1];
    const int*   seed = (const int*)d_in[2];
    const float* w0 = (const float*)d_in[3];
    const float* b0 = (const float*)d_in[4];
    const float* g0 = (const float*)d_in[5];
    const float* be0 = (const float*)d_in[6];
    const float* m0 = (const float*)d_in[7];
    const float* v0 = (const float*)d_in[8];
    const float* w1 = (const float*)d_in[9];
    const float* b1 = (const float*)d_in[10];
    const float* g1 = (const float*)d_in[11];
    const float* be1 = (const float*)d_in[12];
    const float* m1 = (const float*)d_in[13];
    const float* v1 = (const float*)d_in[14];
    const float* w2 = (const float*)d_in[15];
    const float* b2 = (const float*)d_in[16];
    const float* g2 = (const float*)d_in[17];
    const float* be2 = (const float*)d_in[18];
    const float* m2 = (const float*)d_in[19];
    const float* v2 = (const float*)d_in[20];
    float* out = (float*)d_out;

    short* wbf = nullptr;
    if (ws_size >= 12288 * sizeof(short)) {
        wbf = (short*)d_ws;
        wconv_kernel<<<dim3(48), dim3(256), 0, stream>>>(w1, w2, wbf);
    }

    fps_kernel<<<dim3(B_ / 2), dim3(FPS_T), 0, stream>>>(xyz, out);
    down_kernel<<<dim3(B_ * S_), dim3(256), 0, stream>>>(xyz, pts, seed,
        w0, b0, g0, be0, m0, v0,
        w1, b1, g1, be1, m1, v1,
        w2, b2, g2, be2, m2, v2,
        out, wbf);
}

// Round 10
// 1238.555 us; speedup vs baseline: 1.5542x; 1.5542x over previous
//
#include <hip/hip_runtime.h>

#define B_ 8
#define N_ 8192
#define S_ 1024
#define NS_ 64

typedef float v2f __attribute__((ext_vector_type(2)));
typedef unsigned long long u64;
typedef short bf16x8 __attribute__((ext_vector_type(8)));
typedef float f32x4 __attribute__((ext_vector_type(4)));

// out layout (floats)
#define OUT0 0                 // new_xyz (B,3,1024)
#define OUT1 24576             // new_points (B,128,1024)
#define OUT2 1073152           // new_seed (B,1024); fps int-bits until down_kernel converts

// ---------------------------------------------------------------------------
// DPP 64-lane reductions (row_shr 1/2/4/8, row_bcast 15/31; result lane 63).
// HW-validated on gfx950 in rounds 6-17.
// ---------------------------------------------------------------------------
template <int CTRL>
static __device__ __forceinline__ float dpp_max_step(float v) {
    int o = __builtin_amdgcn_update_dpp(__float_as_int(v), __float_as_int(v),
                                        CTRL, 0xf, 0xf, false);
    return fmaxf(v, __int_as_float(o));
}
static __device__ __forceinline__ float wave_max_f32(float v) {
    v = dpp_max_step<0x111>(v);
    v = dpp_max_step<0x112>(v);
    v = dpp_max_step<0x114>(v);
    v = dpp_max_step<0x118>(v);
    v = dpp_max_step<0x142>(v);
    v = dpp_max_step<0x143>(v);
    return __int_as_float(__builtin_amdgcn_readlane(__float_as_int(v), 63));
}
template <int CTRL>
static __device__ __forceinline__ unsigned dpp_umin_step(unsigned v) {
    unsigned o = (unsigned)__builtin_amdgcn_update_dpp((int)v, (int)v,
                                                       CTRL, 0xf, 0xf, false);
    return v < o ? v : o;
}
static __device__ __forceinline__ unsigned wave_min_u32(unsigned v) {
    v = dpp_umin_step<0x111>(v);
    v = dpp_umin_step<0x112>(v);
    v = dpp_umin_step<0x114>(v);
    v = dpp_umin_step<0x118>(v);
    v = dpp_umin_step<0x142>(v);
    v = dpp_umin_step<0x143>(v);
    return (unsigned)__builtin_amdgcn_readlane((int)v, 63);
}

// round-to-nearest-even f32 -> bf16 bits
static __device__ __forceinline__ short f2bf(float f) {
    unsigned u = __float_as_uint(f);
    return (short)((u + 0x7FFFu + ((u >> 16) & 1u)) >> 16);
}

// ---------------------------------------------------------------------------
// Kernel 1: farthest point sampling — R6 configuration, BEST MEASURED
// (1234.2 us total, fps 1010 us). One block (256 thr, 4 waves, 1 wave/SIMD)
// per batch; J=16 (32 pts/thread). Per step: dist update (contract(off),
// bit-exact vs reference), mask vs LOCAL max scheduled under the DPP
// wave-max chain, u32 wave-min tie-break, per-wave u64 LDS slot write +
// s_barrier + 3-compare max (parity-double-buffered slots), oseed in LDS
// with one coalesced dump at the end.
// Structural map (all measured, do NOT retry):
//   R18 4-wave restructure alone: -4%          R19/R20 multi-CU global sync:
//   flag lines bounce through HBM, ~4400 cy/step => 2100 us
//   R21 LDS tag-spin + fused u64 DPP argmax: +100 us
//   R22 inline-asm v_pk_*: +154 us (blocks scheduling, +16 VGPR)
//   R24 VGPR pinning via empty asm: no-op (VGPR stays 84; cloud in AGPRs);
//       max3 + b128 slot read: neutral (reverted)
//   R25 two batches/CU: -68% (workgroup-wide s_barrier couples the halves'
//       critical paths; no partial barriers on CDNA)
//   R8/R10 LDS coord arrays; R13/R14 concurrent fps/down fusion: negative.
// Remaining per-step ~2360 cy = ~1000-1100 issue (incl. AGPR-shuffle tax on
// the 128-float cloud) + ~1300 serial latency (DPP chains, barrier skew,
// slot read, L2 centroid load) unhideable at 1 wave/SIMD.
// ---------------------------------------------------------------------------
#define FPS_T 256
#define FPS_J 16    // v2f per thread (32 points)

__global__ __launch_bounds__(FPS_T, 1) void fps_kernel(const float* __restrict__ xyz,
                                                       float* out) {
    const int b = blockIdx.x;
    const int t = threadIdx.x;          // 0..255
    const int lane = t & 63;
    const int wq = t >> 6;              // 0..3
    const float* X = xyz + b * 3 * N_;

    v2f px2[FPS_J], py2[FPS_J], pz2[FPS_J], dist2[FPS_J];
#pragma unroll
    for (int j = 0; j < FPS_J; ++j) {
        int n = t + 512 * j;            // .x -> n, .y -> n + 256
        px2[j] = (v2f){X[n], X[n + 256]};
        py2[j] = (v2f){X[N_ + n], X[N_ + n + 256]};
        pz2[j] = (v2f){X[2 * N_ + n], X[2 * N_ + n + 256]};
        dist2[j] = (v2f){1e10f, 1e10f};
    }

    __shared__ u64 slots[8];            // [parity*4 + wave]
    __shared__ float seedL[S_];

    int ci = 0;
    float c0 = X[0], c1 = X[N_], c2 = X[2 * N_];

    for (int step = 0; step < S_; ++step) {
        if (t == 0) seedL[step] = __int_as_float(ci);

        v2f mv = (v2f){-1.0f, -1.0f};
        {
#pragma clang fp contract(off)
            v2f c0v = (v2f){c0, c0};
            v2f c1v = (v2f){c1, c1};
            v2f c2v = (v2f){c2, c2};
#pragma unroll
            for (int j = 0; j < FPS_J; ++j) {
                v2f e0 = px2[j] - c0v;
                v2f e1 = py2[j] - c1v;
                v2f e2 = pz2[j] - c2v;
                v2f q0 = e0 * e0;
                v2f q1 = e1 * e1;
                v2f q2 = e2 * e2;
                v2f d  = (q0 + q1) + q2;
                v2f dm = __builtin_elementwise_min(dist2[j], d);
                dist2[j] = dm;
                mv = __builtin_elementwise_max(mv, dm);
            }
        }
        float m = fmaxf(mv.x, mv.y);    // lane-local max of 32 elems

        // mask vs LOCAL max — independent of the DPP chain below, so the
        // compiler schedules it under the wave_max latency.
        unsigned mask = 0u;
#pragma unroll
        for (int j = 0; j < FPS_J; ++j) {
            if (dist2[j].x == m) mask |= (1u << (2 * j));
            if (dist2[j].y == m) mask |= (1u << (2 * j + 1));
        }
        float wmax = wave_max_f32(m);

        unsigned c = (unsigned)(__ffs(mask) - 1);   // mask != 0 always
        unsigned cand = (m == wmax) ? ((unsigned)t | (c << 8)) : 0xffffffffu;
        unsigned widx = wave_min_u32(cand);

        if (lane == 63) {
            u64 key = ((u64)__float_as_uint(wmax) << 13) | (u64)(8191u - widx);
            slots[((step & 1) << 2) + wq] = key;
        }
        __syncthreads();

        const u64* sp = &slots[(step & 1) << 2];
        u64 k0 = sp[0], k1 = sp[1], k2 = sp[2], k3 = sp[3];
        u64 ka = (k0 > k1) ? k0 : k1;
        u64 kb = (k2 > k3) ? k2 : k3;
        u64 km = (ka > kb) ? ka : kb;
        ci = 8191 - (int)(km & 0x1fffull);

        int cu = __builtin_amdgcn_readfirstlane(ci);
        c0 = X[cu];
        c1 = X[N_ + cu];
        c2 = X[2 * N_ + cu];
    }

    __syncthreads();                    // seedL fully written
    float* oseed = out + OUT2 + b * S_;
#pragma unroll
    for (int k = 0; k < 4; ++k)
        oseed[t + 256 * k] = seedL[t + 256 * k];
}

// ---------------------------------------------------------------------------
// Kernel 1b: one-shot weight conversion w1 (64x64) + w2 (128x64) -> bf16 in
// d_ws. Shared by all 8192 down_kernel blocks.
// ---------------------------------------------------------------------------
__global__ __launch_bounds__(256) void wconv_kernel(const float* __restrict__ w1,
                                                    const float* __restrict__ w2,
                                                    short* __restrict__ wbf) {
    int t = blockIdx.x * 256 + threadIdx.x;   // 0..12287
    float v = (t < 4096) ? w1[t] : w2[t - 4096];
    wbf[t] = f2bf(v);
}

// ---------------------------------------------------------------------------
// Kernel 2: fused downstream — one block (256 thr, 4 waves) per centroid:
//   (a) read fps idx bits from OUT2 (broadcast), write new_xyz + new_seed
//   (b) 4-wave ball query, FIXED 16-iteration loop
//   (c) MFMA mlp (R16-verified layouts); weights from pre-converted bf16
//       d_ws when available (wbf != nullptr), else inline f2bf fallback.
// ---------------------------------------------------------------------------
__global__ __launch_bounds__(256) void down_kernel(
    const float* __restrict__ xyz, const float* __restrict__ pts,
    const int* __restrict__ seed,
    const float* __restrict__ w0, const float* __restrict__ b0,
    const float* __restrict__ g0, const float* __restrict__ be0,
    const float* __restrict__ m0, const float* __restrict__ v0,
    const float* __restrict__ w1, const float* __restrict__ b1,
    const float* __restrict__ g1, const float* __restrict__ be1,
    const float* __restrict__ m1, const float* __restrict__ v1,
    const float* __restrict__ w2, const float* __restrict__ b2,
    const float* __restrict__ g2, const float* __restrict__ be2,
    const float* __restrict__ m2, const float* __restrict__ v2,
    float* out, const short* __restrict__ wbf) {
    const int sg = blockIdx.x;
    const int b = sg >> 10, s = sg & 1023;
    const int t = threadIdx.x;
    const int lane = t & 63;
    const int wq = __builtin_amdgcn_readfirstlane(t >> 6);   // 0..3
    const int ln = lane & 15;
    const int quad = (lane >> 4) & 3;

    __shared__ float f0[64 * 9];
    __shared__ short featA[64 * 72];
    __shared__ short featB[64 * 72];
    __shared__ float wmaxs[4 * 132];
    __shared__ float scs[256], ofs[256];
    __shared__ int cand[4 * 64];
    __shared__ int cnts[4];
    __shared__ int gis[64];

    const float* X = xyz + b * 3 * N_;

    // (a) broadcast read of fps index; centroid coords
    int ci = __float_as_int(out[OUT2 + sg]) & 8191;
    float cx = X[ci], cy = X[N_ + ci], cz = X[2 * N_ + ci];

    // per-channel BN fold (one sqrt+div per thread)
    {
        float sc, of;
        if (t < 64) {
            int c = t;
            sc = g0[c] / sqrtf(v0[c] + 1e-5f);
            of = (b0[c] - m0[c]) * sc + be0[c];
        } else if (t < 128) {
            int c = t - 64;
            sc = g1[c] / sqrtf(v1[c] + 1e-5f);
            of = (b1[c] - m1[c]) * sc + be1[c];
        } else {
            int c = t - 128;
            sc = g2[c] / sqrtf(v2[c] + 1e-5f);
            of = (b2[c] - m2[c]) * sc + be2[c];
        }
        scs[t] = sc;
        ofs[t] = of;
    }
    __syncthreads();   // all OUT2 reads complete (vmcnt drained) before overwrite

    if (t == 0) {
        out[OUT0 + (b * 3 + 0) * S_ + s] = cx;
        out[OUT0 + (b * 3 + 1) * S_ + s] = cy;
        out[OUT0 + (b * 3 + 2) * S_ + s] = cz;
        out[OUT2 + sg] = (float)seed[b * N_ + ci];
    }

    // (b) 4-wave ball query: wave wq scans [2048*wq, 2048*wq+2048), 16 iters
    {
        int cnt = 0;
        const int wbase = wq << 11;
#pragma unroll 2
        for (int base = 0; base < 2048; base += 128) {
            int n0 = wbase + base + lane;
            int n1 = n0 + 64;
            float x0 = X[n0], y0 = X[N_ + n0], z0 = X[2 * N_ + n0];
            float x1 = X[n1], y1 = X[N_ + n1], z1 = X[2 * N_ + n1];
            float e0 = x0 - cx, e1 = y0 - cy, e2 = z0 - cz;
            float d0 = fmaf(e2, e2, fmaf(e1, e1, e0 * e0));
            float q0 = x1 - cx, q1 = y1 - cy, q2 = z1 - cz;
            float d1 = fmaf(q2, q2, fmaf(q1, q1, q0 * q0));

            u64 mask0 = __ballot(d0 <= 0.04f);
            if (mask0) {
                int pos = cnt + (int)__popcll(mask0 & ((1ull << lane) - 1ull));
                if ((d0 <= 0.04f) && pos < NS_) cand[(wq << 6) + pos] = n0;
                cnt += (int)__popcll(mask0);
            }
            u64 mask1 = __ballot(d1 <= 0.04f);
            if (mask1) {
                int pos = cnt + (int)__popcll(mask1 & ((1ull << lane) - 1ull));
                if ((d1 <= 0.04f) && pos < NS_) cand[(wq << 6) + pos] = n1;
                cnt += (int)__popcll(mask1);
            }
        }
        if (lane == 0) cnts[wq] = cnt;
    }
    __syncthreads();

    // merge: first 64 in global ascending index order; pad with overall-first
    if (t < 64) {
        int k = t;
        int start = 0, sel = -1, firstv = -1;
#pragma unroll
        for (int w = 0; w < 4; ++w) {
            int cw = min(cnts[w], NS_);
            if (firstv < 0 && cw > 0) firstv = cand[(w << 6)];
            if (sel < 0 && k < start + cw) sel = cand[(w << 6) + (k - start)];
            start += cw;
        }
        if (sel < 0) sel = firstv;
        gis[t] = sel;
    }
    __syncthreads();

    if (t < 64) {
        int gidx = gis[t] & 8191;
        const float* P = pts + b * 3 * N_;
        f0[t * 9 + 0] = X[gidx] - cx;
        f0[t * 9 + 1] = X[N_ + gidx] - cy;
        f0[t * 9 + 2] = X[2 * N_ + gidx] - cz;
        f0[t * 9 + 3] = P[gidx];
        f0[t * 9 + 4] = P[N_ + gidx];
        f0[t * 9 + 5] = P[2 * N_ + gidx];
    }
    __syncthreads();

    // (c) layer 0: 6 -> 64 on VALU; point = lane, wave owns 16-channel slice
    {
        float in[6];
#pragma unroll
        for (int c = 0; c < 6; ++c) in[c] = f0[lane * 9 + c];
#pragma unroll 1
        for (int i = 0; i < 16; i += 4) {
            int o = wq * 16 + i;
            float a0 = 0.f, a1 = 0.f, a2 = 0.f, a3 = 0.f;
#pragma unroll
            for (int c = 0; c < 6; ++c) {
                float rc = in[c];
                a0 = fmaf(rc, w0[(o + 0) * 6 + c], a0);
                a1 = fmaf(rc, w0[(o + 1) * 6 + c], a1);
                a2 = fmaf(rc, w0[(o + 2) * 6 + c], a2);
                a3 = fmaf(rc, w0[(o + 3) * 6 + c], a3);
            }
            featA[lane * 72 + o + 0] = f2bf(fmaxf(fmaf(a0, scs[o + 0], ofs[o + 0]), 0.f));
            featA[lane * 72 + o + 1] = f2bf(fmaxf(fmaf(a1, scs[o + 1], ofs[o + 1]), 0.f));
            featA[lane * 72 + o + 2] = f2bf(fmaxf(fmaf(a2, scs[o + 2], ofs[o + 2]), 0.f));
            featA[lane * 72 + o + 3] = f2bf(fmaxf(fmaf(a3, scs[o + 3], ofs[o + 3]), 0.f));
        }
    }
    __syncthreads();

    const int arow = 16 * wq + ln;   // this wave's m-tile row for A-frags
    const bool usebf = (wbf != nullptr);

    // layer 1: 64 -> 64 via MFMA (4 ntiles x 2 ksteps)
    {
        bf16x8 a1f[2];
#pragma unroll
        for (int ks = 0; ks < 2; ++ks)
            a1f[ks] = *(const bf16x8*)&featA[arow * 72 + ks * 32 + quad * 8];

#pragma unroll
        for (int nt = 0; nt < 4; ++nt) {
            f32x4 acc = {0.f, 0.f, 0.f, 0.f};
#pragma unroll
            for (int ks = 0; ks < 2; ++ks) {
                int off = (nt * 16 + ln) * 64 + ks * 32 + quad * 8;
                bf16x8 bf;
                if (usebf) {
                    bf = *(const bf16x8*)&wbf[off];
                } else {
                    const float* wr = w1 + off;
                    float4 p = *(const float4*)wr;
                    float4 q = *(const float4*)(wr + 4);
                    bf = (bf16x8){f2bf(p.x), f2bf(p.y), f2bf(p.z), f2bf(p.w),
                                  f2bf(q.x), f2bf(q.y), f2bf(q.z), f2bf(q.w)};
                }
                acc = __builtin_amdgcn_mfma_f32_16x16x32_bf16(a1f[ks], bf, acc, 0, 0, 0);
            }
            int o = nt * 16 + ln;
            float sc = scs[64 + o], of = ofs[64 + o];
#pragma unroll
            for (int reg = 0; reg < 4; ++reg) {
                float y = fmaxf(fmaf(acc[reg], sc, of), 0.f);
                featB[(16 * wq + quad * 4 + reg) * 72 + o] = f2bf(y);
            }
        }
    }
    // no barrier: each wave reads back only its own m-tile rows

    // layer 2: 64 -> 128 via MFMA (8 ntiles x 2 ksteps) + fused k-max
    {
        bf16x8 a2f[2];
#pragma unroll
        for (int ks = 0; ks < 2; ++ks)
            a2f[ks] = *(const bf16x8*)&featB[arow * 72 + ks * 32 + quad * 8];

#pragma unroll
        for (int nt = 0; nt < 8; ++nt) {
            f32x4 acc = {0.f, 0.f, 0.f, 0.f};
#pragma unroll
            for (int ks = 0; ks < 2; ++ks) {
                int off = (nt * 16 + ln) * 64 + ks * 32 + quad * 8;
                bf16x8 bf;
                if (usebf) {
                    bf = *(const bf16x8*)&wbf[4096 + off];
                } else {
                    const float* wr = w2 + off;
                    float4 p = *(const float4*)wr;
                    float4 q = *(const float4*)(wr + 4);
                    bf = (bf16x8){f2bf(p.x), f2bf(p.y), f2bf(p.z), f2bf(p.w),
                                  f2bf(q.x), f2bf(q.y), f2bf(q.z), f2bf(q.w)};
                }
                acc = __builtin_amdgcn_mfma_f32_16x16x32_bf16(a2f[ks], bf, acc, 0, 0, 0);
            }
            int o = nt * 16 + ln;
            float sc = scs[128 + o], of = ofs[128 + o];
            float m = -1.f;
#pragma unroll
            for (int reg = 0; reg < 4; ++reg) {
                float y = fmaxf(fmaf(acc[reg], sc, of), 0.f);
                m = fmaxf(m, y);
            }
            m = fmaxf(m, __shfl_xor(m, 16, 64));
            m = fmaxf(m, __shfl_xor(m, 32, 64));
            if (lane < 16) wmaxs[wq * 132 + o] = m;
        }
    }
    __syncthreads();

    // final: max over the 4 waves' m-tiles, store new_points
    if (t < 128) {
        float m = fmaxf(fmaxf(wmaxs[0 * 132 + t], wmaxs[1 * 132 + t]),
                        fmaxf(wmaxs[2 * 132 + t], wmaxs[3 * 132 + t]));
        out[OUT1 + (b * 128 + t) * S_ + s] = m;
    }
}

extern "C" void kernel_launch(void* const* d_in, const int* in_sizes, int n_in,
                              void* d_out, int out_size, void* d_ws, size_t ws_size,
                              hipStream_t stream) {
    const float* xyz  = (const float*)d_in[0];
    const float* pts  = (const float*)d_in[1];
    const int*   seed = (const int*)d_in[2];
    const float* w0 = (const float*)d_in[3];
    const float* b0 = (const float*)d_in[4];
    const float* g0 = (const float*)d_in[5];
    const float* be0 = (const float*)d_in[6];
    const float* m0 = (const float*)d_in[7];
    const float* v0 = (const float*)d_in[8];
    const float* w1 = (const float*)d_in[9];
    const float* b1 = (const float*)d_in[10];
    const float* g1 = (const float*)d_in[11];
    const float* be1 = (const float*)d_in[12];
    const float* m1 = (const float*)d_in[13];
    const float* v1 = (const float*)d_in[14];
    const float* w2 = (const float*)d_in[15];
    const float* b2 = (const float*)d_in[16];
    const float* g2 = (const float*)d_in[17];
    const float* be2 = (const float*)d_in[18];
    const float* m2 = (const float*)d_in[19];
    const float* v2 = (const float*)d_in[20];
    float* out = (float*)d_out;

    short* wbf = nullptr;
    if (ws_size >= 12288 * sizeof(short)) {
        wbf = (short*)d_ws;
        wconv_kernel<<<dim3(48), dim3(256), 0, stream>>>(w1, w2, wbf);
    }

    fps_kernel<<<dim3(B_), dim3(FPS_T), 0, stream>>>(xyz, out);
    down_kernel<<<dim3(B_ * S_), dim3(256), 0, stream>>>(xyz, pts, seed,
        w0, b0, g0, be0, m0, v0,
        w1, b1, g1, be1, m1, v1,
        w2, b2, g2, be2, m2, v2,
        out, wbf);
}

// Round 11
// 1207.789 us; speedup vs baseline: 1.5938x; 1.0255x over previous
//
#include <hip/hip_runtime.h>

#define B_ 8
#define N_ 8192
#define S_ 1024
#define NS_ 64

typedef float v2f __attribute__((ext_vector_type(2)));
typedef unsigned long long u64;
typedef short bf16x8 __attribute__((ext_vector_type(8)));
typedef float f32x4 __attribute__((ext_vector_type(4)));

// out layout (floats)
#define OUT0 0                 // new_xyz (B,3,1024)
#define OUT1 24576             // new_points (B,128,1024)
#define OUT2 1073152           // new_seed (B,1024); fps int-bits until down_kernel converts

// ---------------------------------------------------------------------------
// DPP 64-lane reductions (row_shr 1/2/4/8, row_bcast 15/31; result lane 63).
// HW-validated on gfx950 in rounds 6-17.
// ---------------------------------------------------------------------------
template <int CTRL>
static __device__ __forceinline__ float dpp_max_step(float v) {
    int o = __builtin_amdgcn_update_dpp(__float_as_int(v), __float_as_int(v),
                                        CTRL, 0xf, 0xf, false);
    return fmaxf(v, __int_as_float(o));
}
static __device__ __forceinline__ float wave_max_f32(float v) {
    v = dpp_max_step<0x111>(v);
    v = dpp_max_step<0x112>(v);
    v = dpp_max_step<0x114>(v);
    v = dpp_max_step<0x118>(v);
    v = dpp_max_step<0x142>(v);
    v = dpp_max_step<0x143>(v);
    return __int_as_float(__builtin_amdgcn_readlane(__float_as_int(v), 63));
}
template <int CTRL>
static __device__ __forceinline__ unsigned dpp_umin_step(unsigned v) {
    unsigned o = (unsigned)__builtin_amdgcn_update_dpp((int)v, (int)v,
                                                       CTRL, 0xf, 0xf, false);
    return v < o ? v : o;
}
static __device__ __forceinline__ unsigned wave_min_u32(unsigned v) {
    v = dpp_umin_step<0x111>(v);
    v = dpp_umin_step<0x112>(v);
    v = dpp_umin_step<0x114>(v);
    v = dpp_umin_step<0x118>(v);
    v = dpp_umin_step<0x142>(v);
    v = dpp_umin_step<0x143>(v);
    return (unsigned)__builtin_amdgcn_readlane((int)v, 63);
}

// round-to-nearest-even f32 -> bf16 bits
static __device__ __forceinline__ short f2bf(float f) {
    unsigned u = __float_as_uint(f);
    return (short)((u + 0x7FFFu + ((u >> 16) & 1u)) >> 16);
}

// ---------------------------------------------------------------------------
// Kernel 1: farthest point sampling — R6 structure (best measured: fps 1010-
// 1017 us) + R26 step-tail compression:
//  (1) cloud staged ONCE into LDS as float4[8192] (128 KB; 1 block/CU so
//      the 160 KB budget holds; >64KB static LDS is gfx950-supported per
//      learn_hip m201/m243). NOT the R8/R10 negative (that was inner-loop
//      coord reads from LDS; the inner loop stays in registers).
//  (2) step tail: after the slot ds_read, ALL FOUR candidates' coords are
//      fetched speculatively (4x broadcast ds_read_b128) while the u64
//      compares resolve, then the winner is picked with cndmask selects.
//      Replaces compare -> readfirstlane -> 3 scalar L2 loads (~200 cy) on
//      the serial chain with overlapped LDS reads (~120 cy, issued earlier).
//      Staged coords are bit-exact copies; key compare order unchanged =>
//      selection and outputs bit-identical.
// Structural map (all measured, do NOT retry):
//   R18 4-wave-alone: -4% | R19/R20 multi-CU global sync: ~4400 cy/step
//   (flag lines bounce through HBM) | R21 LDS tag-spin + fused u64 argmax:
//   +100 us | R22 inline-asm v_pk_*: +154 us | R24 VGPR pin: no-op;
//   max3/b128: neutral | R25 two batches/CU: -68% (shared s_barrier couples
//   the halves) | R8/R10 LDS inner-loop coords, R13/R14 concurrent fusion:
//   negative.
// Remaining/step ~2360 cy = ~1400 issue + ~950 serial latency.
// ---------------------------------------------------------------------------
#define FPS_T 256
#define FPS_J 16    // v2f per thread (32 points)

__global__ __launch_bounds__(FPS_T, 1) void fps_kernel(const float* __restrict__ xyz,
                                                       float* out) {
    const int b = blockIdx.x;
    const int t = threadIdx.x;          // 0..255
    const int lane = t & 63;
    const int wq = t >> 6;              // 0..3
    const float* X = xyz + b * 3 * N_;

    __shared__ float4 xyzq[N_];         // 128 KB staged cloud
    __shared__ u64 slots[8];            // [parity*4 + wave]
    __shared__ float seedL[S_];

    v2f px2[FPS_J], py2[FPS_J], pz2[FPS_J], dist2[FPS_J];
#pragma unroll
    for (int j = 0; j < FPS_J; ++j) {
        int n = t + 512 * j;            // .x -> n, .y -> n + 256
        float x0 = X[n],          x1 = X[n + 256];
        float y0 = X[N_ + n],     y1 = X[N_ + n + 256];
        float z0 = X[2 * N_ + n], z1 = X[2 * N_ + n + 256];
        px2[j] = (v2f){x0, x1};
        py2[j] = (v2f){y0, y1};
        pz2[j] = (v2f){z0, z1};
        dist2[j] = (v2f){1e10f, 1e10f};
        xyzq[n]       = make_float4(x0, y0, z0, 0.f);
        xyzq[n + 256] = make_float4(x1, y1, z1, 0.f);
    }
    __syncthreads();                    // staged cloud visible to all waves

    int ci = 0;
    float c0 = X[0], c1 = X[N_], c2 = X[2 * N_];

    for (int step = 0; step < S_; ++step) {
        if (t == 0) seedL[step] = __int_as_float(ci);

        v2f mv = (v2f){-1.0f, -1.0f};
        {
#pragma clang fp contract(off)
            v2f c0v = (v2f){c0, c0};
            v2f c1v = (v2f){c1, c1};
            v2f c2v = (v2f){c2, c2};
#pragma unroll
            for (int j = 0; j < FPS_J; ++j) {
                v2f e0 = px2[j] - c0v;
                v2f e1 = py2[j] - c1v;
                v2f e2 = pz2[j] - c2v;
                v2f q0 = e0 * e0;
                v2f q1 = e1 * e1;
                v2f q2 = e2 * e2;
                v2f d  = (q0 + q1) + q2;
                v2f dm = __builtin_elementwise_min(dist2[j], d);
                dist2[j] = dm;
                mv = __builtin_elementwise_max(mv, dm);
            }
        }
        float m = fmaxf(mv.x, mv.y);    // lane-local max of 32 elems

        // mask vs LOCAL max — independent of the DPP chain below, so the
        // compiler schedules it under the wave_max latency.
        unsigned mask = 0u;
#pragma unroll
        for (int j = 0; j < FPS_J; ++j) {
            if (dist2[j].x == m) mask |= (1u << (2 * j));
            if (dist2[j].y == m) mask |= (1u << (2 * j + 1));
        }
        float wmax = wave_max_f32(m);

        unsigned c = (unsigned)(__ffs(mask) - 1);   // mask != 0 always
        unsigned cand = (m == wmax) ? ((unsigned)t | (c << 8)) : 0xffffffffu;
        unsigned widx = wave_min_u32(cand);

        if (lane == 63) {
            u64 key = ((u64)__float_as_uint(wmax) << 13) | (u64)(8191u - widx);
            slots[((step & 1) << 2) + wq] = key;
        }
        __syncthreads();

        // slots -> 4 candidate indices -> speculative broadcast ds_read_b128
        // of all 4 coords; u64 compares resolve under the LDS latency; winner
        // picked by cndmask selects. ci from the max key as before.
        const u64* sp = &slots[(step & 1) << 2];
        u64 k0 = sp[0], k1 = sp[1], k2 = sp[2], k3 = sp[3];
        int i0 = 8191 - (int)(k0 & 0x1fffull);
        int i1 = 8191 - (int)(k1 & 0x1fffull);
        int i2 = 8191 - (int)(k2 & 0x1fffull);
        int i3 = 8191 - (int)(k3 & 0x1fffull);
        float4 p0 = xyzq[i0];
        float4 p1 = xyzq[i1];
        float4 p2 = xyzq[i2];
        float4 p3 = xyzq[i3];
        bool b01 = k0 > k1, b23 = k2 > k3;
        u64 ka = b01 ? k0 : k1;
        u64 kb = b23 ? k2 : k3;
        float4 pa, pb;
        pa.x = b01 ? p0.x : p1.x; pa.y = b01 ? p0.y : p1.y; pa.z = b01 ? p0.z : p1.z;
        pb.x = b23 ? p2.x : p3.x; pb.y = b23 ? p2.y : p3.y; pb.z = b23 ? p2.z : p3.z;
        bool bab = ka > kb;
        u64 km = bab ? ka : kb;
        ci = 8191 - (int)(km & 0x1fffull);
        c0 = bab ? pa.x : pb.x;
        c1 = bab ? pa.y : pb.y;
        c2 = bab ? pa.z : pb.z;
    }

    __syncthreads();                    // seedL fully written
    float* oseed = out + OUT2 + b * S_;
#pragma unroll
    for (int k = 0; k < 4; ++k)
        oseed[t + 256 * k] = seedL[t + 256 * k];
}

// ---------------------------------------------------------------------------
// Kernel 1b: one-shot weight conversion w1 (64x64) + w2 (128x64) -> bf16 in
// d_ws. Shared by all 8192 down_kernel blocks.
// ---------------------------------------------------------------------------
__global__ __launch_bounds__(256) void wconv_kernel(const float* __restrict__ w1,
                                                    const float* __restrict__ w2,
                                                    short* __restrict__ wbf) {
    int t = blockIdx.x * 256 + threadIdx.x;   // 0..12287
    float v = (t < 4096) ? w1[t] : w2[t - 4096];
    wbf[t] = f2bf(v);
}

// ---------------------------------------------------------------------------
// Kernel 2: fused downstream — one block (256 thr, 4 waves) per centroid:
//   (a) read fps idx bits from OUT2 (broadcast), write new_xyz + new_seed
//   (b) 4-wave ball query, FIXED 16-iteration loop
//   (c) MFMA mlp (R16-verified layouts); weights from pre-converted bf16
//       d_ws when available (wbf != nullptr), else inline f2bf fallback.
// ---------------------------------------------------------------------------
__global__ __launch_bounds__(256) void down_kernel(
    const float* __restrict__ xyz, const float* __restrict__ pts,
    const int* __restrict__ seed,
    const float* __restrict__ w0, const float* __restrict__ b0,
    const float* __restrict__ g0, const float* __restrict__ be0,
    const float* __restrict__ m0, const float* __restrict__ v0,
    const float* __restrict__ w1, const float* __restrict__ b1,
    const float* __restrict__ g1, const float* __restrict__ be1,
    const float* __restrict__ m1, const float* __restrict__ v1,
    const float* __restrict__ w2, const float* __restrict__ b2,
    const float* __restrict__ g2, const float* __restrict__ be2,
    const float* __restrict__ m2, const float* __restrict__ v2,
    float* out, const short* __restrict__ wbf) {
    const int sg = blockIdx.x;
    const int b = sg >> 10, s = sg & 1023;
    const int t = threadIdx.x;
    const int lane = t & 63;
    const int wq = __builtin_amdgcn_readfirstlane(t >> 6);   // 0..3
    const int ln = lane & 15;
    const int quad = (lane >> 4) & 3;

    __shared__ float f0[64 * 9];
    __shared__ short featA[64 * 72];
    __shared__ short featB[64 * 72];
    __shared__ float wmaxs[4 * 132];
    __shared__ float scs[256], ofs[256];
    __shared__ int cand[4 * 64];
    __shared__ int cnts[4];
    __shared__ int gis[64];

    const float* X = xyz + b * 3 * N_;

    // (a) broadcast read of fps index; centroid coords
    int ci = __float_as_int(out[OUT2 + sg]) & 8191;
    float cx = X[ci], cy = X[N_ + ci], cz = X[2 * N_ + ci];

    // per-channel BN fold (one sqrt+div per thread)
    {
        float sc, of;
        if (t < 64) {
            int c = t;
            sc = g0[c] / sqrtf(v0[c] + 1e-5f);
            of = (b0[c] - m0[c]) * sc + be0[c];
        } else if (t < 128) {
            int c = t - 64;
            sc = g1[c] / sqrtf(v1[c] + 1e-5f);
            of = (b1[c] - m1[c]) * sc + be1[c];
        } else {
            int c = t - 128;
            sc = g2[c] / sqrtf(v2[c] + 1e-5f);
            of = (b2[c] - m2[c]) * sc + be2[c];
        }
        scs[t] = sc;
        ofs[t] = of;
    }
    __syncthreads();   // all OUT2 reads complete (vmcnt drained) before overwrite

    if (t == 0) {
        out[OUT0 + (b * 3 + 0) * S_ + s] = cx;
        out[OUT0 + (b * 3 + 1) * S_ + s] = cy;
        out[OUT0 + (b * 3 + 2) * S_ + s] = cz;
        out[OUT2 + sg] = (float)seed[b * N_ + ci];
    }

    // (b) 4-wave ball query: wave wq scans [2048*wq, 2048*wq+2048), 16 iters
    {
        int cnt = 0;
        const int wbase = wq << 11;
#pragma unroll 2
        for (int base = 0; base < 2048; base += 128) {
            int n0 = wbase + base + lane;
            int n1 = n0 + 64;
            float x0 = X[n0], y0 = X[N_ + n0], z0 = X[2 * N_ + n0];
            float x1 = X[n1], y1 = X[N_ + n1], z1 = X[2 * N_ + n1];
            float e0 = x0 - cx, e1 = y0 - cy, e2 = z0 - cz;
            float d0 = fmaf(e2, e2, fmaf(e1, e1, e0 * e0));
            float q0 = x1 - cx, q1 = y1 - cy, q2 = z1 - cz;
            float d1 = fmaf(q2, q2, fmaf(q1, q1, q0 * q0));

            u64 mask0 = __ballot(d0 <= 0.04f);
            if (mask0) {
                int pos = cnt + (int)__popcll(mask0 & ((1ull << lane) - 1ull));
                if ((d0 <= 0.04f) && pos < NS_) cand[(wq << 6) + pos] = n0;
                cnt += (int)__popcll(mask0);
            }
            u64 mask1 = __ballot(d1 <= 0.04f);
            if (mask1) {
                int pos = cnt + (int)__popcll(mask1 & ((1ull << lane) - 1ull));
                if ((d1 <= 0.04f) && pos < NS_) cand[(wq << 6) + pos] = n1;
                cnt += (int)__popcll(mask1);
            }
        }
        if (lane == 0) cnts[wq] = cnt;
    }
    __syncthreads();

    // merge: first 64 in global ascending index order; pad with overall-first
    if (t < 64) {
        int k = t;
        int start = 0, sel = -1, firstv = -1;
#pragma unroll
        for (int w = 0; w < 4; ++w) {
            int cw = min(cnts[w], NS_);
            if (firstv < 0 && cw > 0) firstv = cand[(w << 6)];
            if (sel < 0 && k < start + cw) sel = cand[(w << 6) + (k - start)];
            start += cw;
        }
        if (sel < 0) sel = firstv;
        gis[t] = sel;
    }
    __syncthreads();

    if (t < 64) {
        int gidx = gis[t] & 8191;
        const float* P = pts + b * 3 * N_;
        f0[t * 9 + 0] = X[gidx] - cx;
        f0[t * 9 + 1] = X[N_ + gidx] - cy;
        f0[t * 9 + 2] = X[2 * N_ + gidx] - cz;
        f0[t * 9 + 3] = P[gidx];
        f0[t * 9 + 4] = P[N_ + gidx];
        f0[t * 9 + 5] = P[2 * N_ + gidx];
    }
    __syncthreads();

    // (c) layer 0: 6 -> 64 on VALU; point = lane, wave owns 16-channel slice
    {
        float in[6];
#pragma unroll
        for (int c = 0; c < 6; ++c) in[c] = f0[lane * 9 + c];
#pragma unroll 1
        for (int i = 0; i < 16; i += 4) {
            int o = wq * 16 + i;
            float a0 = 0.f, a1 = 0.f, a2 = 0.f, a3 = 0.f;
#pragma unroll
            for (int c = 0; c < 6; ++c) {
                float rc = in[c];
                a0 = fmaf(rc, w0[(o + 0) * 6 + c], a0);
                a1 = fmaf(rc, w0[(o + 1) * 6 + c], a1);
                a2 = fmaf(rc, w0[(o + 2) * 6 + c], a2);
                a3 = fmaf(rc, w0[(o + 3) * 6 + c], a3);
            }
            featA[lane * 72 + o + 0] = f2bf(fmaxf(fmaf(a0, scs[o + 0], ofs[o + 0]), 0.f));
            featA[lane * 72 + o + 1] = f2bf(fmaxf(fmaf(a1, scs[o + 1], ofs[o + 1]), 0.f));
            featA[lane * 72 + o + 2] = f2bf(fmaxf(fmaf(a2, scs[o + 2], ofs[o + 2]), 0.f));
            featA[lane * 72 + o + 3] = f2bf(fmaxf(fmaf(a3, scs[o + 3], ofs[o + 3]), 0.f));
        }
    }
    __syncthreads();

    const int arow = 16 * wq + ln;   // this wave's m-tile row for A-frags
    const bool usebf = (wbf != nullptr);

    // layer 1: 64 -> 64 via MFMA (4 ntiles x 2 ksteps)
    {
        bf16x8 a1f[2];
#pragma unroll
        for (int ks = 0; ks < 2; ++ks)
            a1f[ks] = *(const bf16x8*)&featA[arow * 72 + ks * 32 + quad * 8];

#pragma unroll
        for (int nt = 0; nt < 4; ++nt) {
            f32x4 acc = {0.f, 0.f, 0.f, 0.f};
#pragma unroll
            for (int ks = 0; ks < 2; ++ks) {
                int off = (nt * 16 + ln) * 64 + ks * 32 + quad * 8;
                bf16x8 bf;
                if (usebf) {
                    bf = *(const bf16x8*)&wbf[off];
                } else {
                    const float* wr = w1 + off;
                    float4 p = *(const float4*)wr;
                    float4 q = *(const float4*)(wr + 4);
                    bf = (bf16x8){f2bf(p.x), f2bf(p.y), f2bf(p.z), f2bf(p.w),
                                  f2bf(q.x), f2bf(q.y), f2bf(q.z), f2bf(q.w)};
                }
                acc = __builtin_amdgcn_mfma_f32_16x16x32_bf16(a1f[ks], bf, acc, 0, 0, 0);
            }
            int o = nt * 16 + ln;
            float sc = scs[64 + o], of = ofs[64 + o];
#pragma unroll
            for (int reg = 0; reg < 4; ++reg) {
                float y = fmaxf(fmaf(acc[reg], sc, of), 0.f);
                featB[(16 * wq + quad * 4 + reg) * 72 + o] = f2bf(y);
            }
        }
    }
    // no barrier: each wave reads back only its own m-tile rows

    // layer 2: 64 -> 128 via MFMA (8 ntiles x 2 ksteps) + fused k-max
    {
        bf16x8 a2f[2];
#pragma unroll
        for (int ks = 0; ks < 2; ++ks)
            a2f[ks] = *(const bf16x8*)&featB[arow * 72 + ks * 32 + quad * 8];

#pragma unroll
        for (int nt = 0; nt < 8; ++nt) {
            f32x4 acc = {0.f, 0.f, 0.f, 0.f};
#pragma unroll
            for (int ks = 0; ks < 2; ++ks) {
                int off = (nt * 16 + ln) * 64 + ks * 32 + quad * 8;
                bf16x8 bf;
                if (usebf) {
                    bf = *(const bf16x8*)&wbf[4096 + off];
                } else {
                    const float* wr = w2 + off;
                    float4 p = *(const float4*)wr;
                    float4 q = *(const float4*)(wr + 4);
                    bf = (bf16x8){f2bf(p.x), f2bf(p.y), f2bf(p.z), f2bf(p.w),
                                  f2bf(q.x), f2bf(q.y), f2bf(q.z), f2bf(q.w)};
                }
                acc = __builtin_amdgcn_mfma_f32_16x16x32_bf16(a2f[ks], bf, acc, 0, 0, 0);
            }
            int o = nt * 16 + ln;
            float sc = scs[128 + o], of = ofs[128 + o];
            float m = -1.f;
#pragma unroll
            for (int reg = 0; reg < 4; ++reg) {
                float y = fmaxf(fmaf(acc[reg], sc, of), 0.f);
                m = fmaxf(m, y);
            }
            m = fmaxf(m, __shfl_xor(m, 16, 64));
            m = fmaxf(m, __shfl_xor(m, 32, 64));
            if (lane < 16) wmaxs[wq * 132 + o] = m;
        }
    }
    __syncthreads();

    // final: max over the 4 waves' m-tiles, store new_points
    if (t < 128) {
        float m = fmaxf(fmaxf(wmaxs[0 * 132 + t], wmaxs[1 * 132 + t]),
                        fmaxf(wmaxs[2 * 132 + t], wmaxs[3 * 132 + t]));
        out[OUT1 + (b * 128 + t) * S_ + s] = m;
    }
}

extern "C" void kernel_launch(void* const* d_in, const int* in_sizes, int n_in,
                              void* d_out, int out_size, void* d_ws, size_t ws_size,
                              hipStream_t stream) {
    const float* xyz  = (const float*)d_in[0];
    const float* pts  = (const float*)d_in[1];
    const int*   seed = (const int*)d_in[2];
    const float* w0 = (const float*)d_in[3];
    const float* b0 = (const float*)d_in[4];
    const float* g0 = (const float*)d_in[5];
    const float* be0 = (const float*)d_in[6];
    const float* m0 = (const float*)d_in[7];
    const float* v0 = (const float*)d_in[8];
    const float* w1 = (const float*)d_in[9];
    const float* b1 = (const float*)d_in[10];
    const float* g1 = (const float*)d_in[11];
    const float* be1 = (const float*)d_in[12];
    const float* m1 = (const float*)d_in[13];
    const float* v1 = (const float*)d_in[14];
    const float* w2 = (const float*)d_in[15];
    const float* b2 = (const float*)d_in[16];
    const float* g2 = (const float*)d_in[17];
    const float* be2 = (const float*)d_in[18];
    const float* m2 = (const float*)d_in[19];
    const float* v2 = (const float*)d_in[20];
    float* out = (float*)d_out;

    short* wbf = nullptr;
    if (ws_size >= 12288 * sizeof(short)) {
        wbf = (short*)d_ws;
        wconv_kernel<<<dim3(48), dim3(256), 0, stream>>>(w1, w2, wbf);
    }

    fps_kernel<<<dim3(B_), dim3(FPS_T), 0, stream>>>(xyz, out);
    down_kernel<<<dim3(B_ * S_), dim3(256), 0, stream>>>(xyz, pts, seed,
        w0, b0, g0, be0, m0, v0,
        w1, b1, g1, be1, m1, v1,
        w2, b2, g2, be2, m2, v2,
        out, wbf);
}

// Round 12
// 1167.634 us; speedup vs baseline: 1.6486x; 1.0344x over previous
//
#include <hip/hip_runtime.h>

#define B_ 8
#define N_ 8192
#define S_ 1024
#define NS_ 64

typedef float v2f __attribute__((ext_vector_type(2)));
typedef unsigned long long u64;
typedef short bf16x8 __attribute__((ext_vector_type(8)));
typedef float f32x4 __attribute__((ext_vector_type(4)));

// out layout (floats)
#define OUT0 0                 // new_xyz (B,3,1024)
#define OUT1 24576             // new_points (B,128,1024)
#define OUT2 1073152           // new_seed (B,1024); fps int-bits until down_kernel converts

// ---------------------------------------------------------------------------
// DPP 64-lane reductions (row_shr 1/2/4/8, row_bcast 15/31; result lane 63).
// HW-validated on gfx950 in rounds 6-17.
// ---------------------------------------------------------------------------
template <int CTRL>
static __device__ __forceinline__ float dpp_max_step(float v) {
    int o = __builtin_amdgcn_update_dpp(__float_as_int(v), __float_as_int(v),
                                        CTRL, 0xf, 0xf, false);
    return fmaxf(v, __int_as_float(o));
}
static __device__ __forceinline__ float wave_max_f32(float v) {
    v = dpp_max_step<0x111>(v);
    v = dpp_max_step<0x112>(v);
    v = dpp_max_step<0x114>(v);
    v = dpp_max_step<0x118>(v);
    v = dpp_max_step<0x142>(v);
    v = dpp_max_step<0x143>(v);
    return __int_as_float(__builtin_amdgcn_readlane(__float_as_int(v), 63));
}
template <int CTRL>
static __device__ __forceinline__ unsigned dpp_umin_step(unsigned v) {
    unsigned o = (unsigned)__builtin_amdgcn_update_dpp((int)v, (int)v,
                                                       CTRL, 0xf, 0xf, false);
    return v < o ? v : o;
}
static __device__ __forceinline__ unsigned wave_min_u32(unsigned v) {
    v = dpp_umin_step<0x111>(v);
    v = dpp_umin_step<0x112>(v);
    v = dpp_umin_step<0x114>(v);
    v = dpp_umin_step<0x118>(v);
    v = dpp_umin_step<0x142>(v);
    v = dpp_umin_step<0x143>(v);
    return (unsigned)__builtin_amdgcn_readlane((int)v, 63);
}

// round-to-nearest-even f32 -> bf16 bits
static __device__ __forceinline__ short f2bf(float f) {
    unsigned u = __float_as_uint(f);
    return (short)((u + 0x7FFFu + ((u >> 16) & 1u)) >> 16);
}

// ---------------------------------------------------------------------------
// Kernel 1: farthest point sampling — R26 configuration, BEST MEASURED
// (fps 980 us, total 1207.8). One block/batch, 256 thr, J=16; cloud staged
// once into LDS float4[8192] (128 KB); step tail = slot ds_read -> 4x
// speculative broadcast ds_read_b128 of candidate coords, u64 compares
// resolve under LDS latency, cndmask select. oseed in LDS, dumped once.
// Structural map (all measured, do NOT retry):
//   R18 4-wave-alone -4% | R19/R20 multi-CU global sync ~4400 cy/step |
//   R21 LDS tag-spin/fused-u64 +100us | R22 inline-asm v_pk_* +154us |
//   R24 VGPR pin no-op; max3/b128 neutral | R25 two batches/CU -68% |
//   R8/R10 LDS inner-loop coords, R13/R14 concurrent fusion: negative.
// Remaining/step ~2300 cy = ~1470 issue (incl. AGPR shuttle) + ~830 latency.
// ---------------------------------------------------------------------------
#define FPS_T 256
#define FPS_J 16    // v2f per thread (32 points)

__global__ __launch_bounds__(FPS_T, 1) void fps_kernel(const float* __restrict__ xyz,
                                                       float* out) {
    const int b = blockIdx.x;
    const int t = threadIdx.x;          // 0..255
    const int lane = t & 63;
    const int wq = t >> 6;              // 0..3
    const float* X = xyz + b * 3 * N_;

    __shared__ float4 xyzq[N_];         // 128 KB staged cloud
    __shared__ u64 slots[8];            // [parity*4 + wave]
    __shared__ float seedL[S_];

    v2f px2[FPS_J], py2[FPS_J], pz2[FPS_J], dist2[FPS_J];
#pragma unroll
    for (int j = 0; j < FPS_J; ++j) {
        int n = t + 512 * j;            // .x -> n, .y -> n + 256
        float x0 = X[n],          x1 = X[n + 256];
        float y0 = X[N_ + n],     y1 = X[N_ + n + 256];
        float z0 = X[2 * N_ + n], z1 = X[2 * N_ + n + 256];
        px2[j] = (v2f){x0, x1};
        py2[j] = (v2f){y0, y1};
        pz2[j] = (v2f){z0, z1};
        dist2[j] = (v2f){1e10f, 1e10f};
        xyzq[n]       = make_float4(x0, y0, z0, 0.f);
        xyzq[n + 256] = make_float4(x1, y1, z1, 0.f);
    }
    __syncthreads();                    // staged cloud visible to all waves

    int ci = 0;
    float c0 = X[0], c1 = X[N_], c2 = X[2 * N_];

    for (int step = 0; step < S_; ++step) {
        if (t == 0) seedL[step] = __int_as_float(ci);

        v2f mv = (v2f){-1.0f, -1.0f};
        {
#pragma clang fp contract(off)
            v2f c0v = (v2f){c0, c0};
            v2f c1v = (v2f){c1, c1};
            v2f c2v = (v2f){c2, c2};
#pragma unroll
            for (int j = 0; j < FPS_J; ++j) {
                v2f e0 = px2[j] - c0v;
                v2f e1 = py2[j] - c1v;
                v2f e2 = pz2[j] - c2v;
                v2f q0 = e0 * e0;
                v2f q1 = e1 * e1;
                v2f q2 = e2 * e2;
                v2f d  = (q0 + q1) + q2;
                v2f dm = __builtin_elementwise_min(dist2[j], d);
                dist2[j] = dm;
                mv = __builtin_elementwise_max(mv, dm);
            }
        }
        float m = fmaxf(mv.x, mv.y);    // lane-local max of 32 elems

        unsigned mask = 0u;
#pragma unroll
        for (int j = 0; j < FPS_J; ++j) {
            if (dist2[j].x == m) mask |= (1u << (2 * j));
            if (dist2[j].y == m) mask |= (1u << (2 * j + 1));
        }
        float wmax = wave_max_f32(m);

        unsigned c = (unsigned)(__ffs(mask) - 1);   // mask != 0 always
        unsigned cand = (m == wmax) ? ((unsigned)t | (c << 8)) : 0xffffffffu;
        unsigned widx = wave_min_u32(cand);

        if (lane == 63) {
            u64 key = ((u64)__float_as_uint(wmax) << 13) | (u64)(8191u - widx);
            slots[((step & 1) << 2) + wq] = key;
        }
        __syncthreads();

        const u64* sp = &slots[(step & 1) << 2];
        u64 k0 = sp[0], k1 = sp[1], k2 = sp[2], k3 = sp[3];
        int i0 = 8191 - (int)(k0 & 0x1fffull);
        int i1 = 8191 - (int)(k1 & 0x1fffull);
        int i2 = 8191 - (int)(k2 & 0x1fffull);
        int i3 = 8191 - (int)(k3 & 0x1fffull);
        float4 p0 = xyzq[i0];
        float4 p1 = xyzq[i1];
        float4 p2 = xyzq[i2];
        float4 p3 = xyzq[i3];
        bool b01 = k0 > k1, b23 = k2 > k3;
        u64 ka = b01 ? k0 : k1;
        u64 kb = b23 ? k2 : k3;
        float4 pa, pb;
        pa.x = b01 ? p0.x : p1.x; pa.y = b01 ? p0.y : p1.y; pa.z = b01 ? p0.z : p1.z;
        pb.x = b23 ? p2.x : p3.x; pb.y = b23 ? p2.y : p3.y; pb.z = b23 ? p2.z : p3.z;
        bool bab = ka > kb;
        u64 km = bab ? ka : kb;
        ci = 8191 - (int)(km & 0x1fffull);
        c0 = bab ? pa.x : pb.x;
        c1 = bab ? pa.y : pb.y;
        c2 = bab ? pa.z : pb.z;
    }

    __syncthreads();                    // seedL fully written
    float* oseed = out + OUT2 + b * S_;
#pragma unroll
    for (int k = 0; k < 4; ++k)
        oseed[t + 256 * k] = seedL[t + 256 * k];
}

// ---------------------------------------------------------------------------
// Kernel 1b: one-shot weight conversion w1 (64x64) + w2 (128x64) -> bf16 in
// d_ws. Shared by all down_kernel blocks.
// ---------------------------------------------------------------------------
__global__ __launch_bounds__(256) void wconv_kernel(const float* __restrict__ w1,
                                                    const float* __restrict__ w2,
                                                    short* __restrict__ wbf) {
    int t = blockIdx.x * 256 + threadIdx.x;   // 0..12287
    float v = (t < 4096) ? w1[t] : w2[t - 4096];
    wbf[t] = f2bf(v);
}

// ---------------------------------------------------------------------------
// Kernel 2 (R27): fused downstream — one block per CENTROID PAIR (4096
// blocks). The latency-bound ball-query scan loads each point ONCE and
// tests it against BOTH centroids (cloud traffic 786->393 MB); MFMA weight
// fragments are loaded once per (nt,ks) and feed TWO MFMAs; BN fold,
// barriers, dispatch amortized 2x. featA/featB merged into one in-place
// buffer feat[cc] (same-wave DS ops are in-order; each wave touches only
// its own 16-row block — same guarantee the old no-barrier trick used).
// Per-centroid arithmetic is op-for-op identical to the verified R16
// layouts => outputs bit-identical to the 1-centroid version.
// ---------------------------------------------------------------------------
__global__ __launch_bounds__(256) void down_kernel(
    const float* __restrict__ xyz, const float* __restrict__ pts,
    const int* __restrict__ seed,
    const float* __restrict__ w0, const float* __restrict__ b0,
    const float* __restrict__ g0, const float* __restrict__ be0,
    const float* __restrict__ m0, const float* __restrict__ v0,
    const float* __restrict__ w1, const float* __restrict__ b1,
    const float* __restrict__ g1, const float* __restrict__ be1,
    const float* __restrict__ m1, const float* __restrict__ v1,
    const float* __restrict__ w2, const float* __restrict__ b2,
    const float* __restrict__ g2, const float* __restrict__ be2,
    const float* __restrict__ m2, const float* __restrict__ v2,
    float* out, const short* __restrict__ wbf) {
    const int sg = blockIdx.x;          // 0..4095
    const int b = sg >> 9, sp = sg & 511;
    const int s0 = sp << 1;             // centroids s0, s0+1
    const int t = threadIdx.x;
    const int lane = t & 63;
    const int wq = __builtin_amdgcn_readfirstlane(t >> 6);   // 0..3
    const int ln = lane & 15;
    const int quad = (lane >> 4) & 3;

    __shared__ float f0[2][64 * 9];
    __shared__ short feat[2][64 * 72];  // layer0 out; layer1 overwrites in place
    __shared__ float wmaxs[2][4 * 132];
    __shared__ float scs[256], ofs[256];
    __shared__ int cand[2][4 * 64];
    __shared__ int cnts[2][4];
    __shared__ int gis[2][64];

    const float* X = xyz + b * 3 * N_;

    // (a) broadcast read of both fps indices; centroid coords
    int ci0 = __float_as_int(out[OUT2 + b * S_ + s0]) & 8191;
    int ci1 = __float_as_int(out[OUT2 + b * S_ + s0 + 1]) & 8191;
    float cx0 = X[ci0], cy0 = X[N_ + ci0], cz0 = X[2 * N_ + ci0];
    float cx1 = X[ci1], cy1 = X[N_ + ci1], cz1 = X[2 * N_ + ci1];

    // per-channel BN fold (one sqrt+div per thread), shared by both centroids
    {
        float sc, of;
        if (t < 64) {
            int c = t;
            sc = g0[c] / sqrtf(v0[c] + 1e-5f);
            of = (b0[c] - m0[c]) * sc + be0[c];
        } else if (t < 128) {
            int c = t - 64;
            sc = g1[c] / sqrtf(v1[c] + 1e-5f);
            of = (b1[c] - m1[c]) * sc + be1[c];
        } else {
            int c = t - 128;
            sc = g2[c] / sqrtf(v2[c] + 1e-5f);
            of = (b2[c] - m2[c]) * sc + be2[c];
        }
        scs[t] = sc;
        ofs[t] = of;
    }
    __syncthreads();   // all OUT2 reads complete (vmcnt drained) before overwrite

    if (t < 2) {
        int cc = t;
        int ci = cc ? ci1 : ci0;
        out[OUT0 + (b * 3 + 0) * S_ + s0 + cc] = cc ? cx1 : cx0;
        out[OUT0 + (b * 3 + 1) * S_ + s0 + cc] = cc ? cy1 : cy0;
        out[OUT0 + (b * 3 + 2) * S_ + s0 + cc] = cc ? cz1 : cz0;
        out[OUT2 + b * S_ + s0 + cc] = (float)seed[b * N_ + ci];
    }

    // (b) 4-wave ball query: wave wq scans [2048*wq, +2048), 16 iters,
    // each point tested against BOTH centroids (loads shared).
    {
        int cnt0 = 0, cnt1 = 0;
        const int wbase = wq << 11;
#pragma unroll 2
        for (int base = 0; base < 2048; base += 128) {
            int n0 = wbase + base + lane;
            int n1 = n0 + 64;
            float x0 = X[n0], y0 = X[N_ + n0], z0 = X[2 * N_ + n0];
            float x1 = X[n1], y1 = X[N_ + n1], z1 = X[2 * N_ + n1];

            float e0 = x0 - cx0, e1 = y0 - cy0, e2 = z0 - cz0;
            float dA0 = fmaf(e2, e2, fmaf(e1, e1, e0 * e0));
            float f0_ = x0 - cx1, f1_ = y0 - cy1, f2_ = z0 - cz1;
            float dB0 = fmaf(f2_, f2_, fmaf(f1_, f1_, f0_ * f0_));
            float q0 = x1 - cx0, q1 = y1 - cy0, q2 = z1 - cz0;
            float dA1 = fmaf(q2, q2, fmaf(q1, q1, q0 * q0));
            float r0 = x1 - cx1, r1 = y1 - cy1, r2 = z1 - cz1;
            float dB1 = fmaf(r2, r2, fmaf(r1, r1, r0 * r0));

            u64 mA0 = __ballot(dA0 <= 0.04f);
            if (mA0) {
                int pos = cnt0 + (int)__popcll(mA0 & ((1ull << lane) - 1ull));
                if ((dA0 <= 0.04f) && pos < NS_) cand[0][(wq << 6) + pos] = n0;
                cnt0 += (int)__popcll(mA0);
            }
            u64 mB0 = __ballot(dB0 <= 0.04f);
            if (mB0) {
                int pos = cnt1 + (int)__popcll(mB0 & ((1ull << lane) - 1ull));
                if ((dB0 <= 0.04f) && pos < NS_) cand[1][(wq << 6) + pos] = n0;
                cnt1 += (int)__popcll(mB0);
            }
            u64 mA1 = __ballot(dA1 <= 0.04f);
            if (mA1) {
                int pos = cnt0 + (int)__popcll(mA1 & ((1ull << lane) - 1ull));
                if ((dA1 <= 0.04f) && pos < NS_) cand[0][(wq << 6) + pos] = n1;
                cnt0 += (int)__popcll(mA1);
            }
            u64 mB1 = __ballot(dB1 <= 0.04f);
            if (mB1) {
                int pos = cnt1 + (int)__popcll(mB1 & ((1ull << lane) - 1ull));
                if ((dB1 <= 0.04f) && pos < NS_) cand[1][(wq << 6) + pos] = n1;
                cnt1 += (int)__popcll(mB1);
            }
        }
        if (lane == 0) { cnts[0][wq] = cnt0; cnts[1][wq] = cnt1; }
    }
    __syncthreads();

    // merge per centroid: first 64 in global ascending index order
    if (t < 128) {
        int cc = t >> 6, k = t & 63;
        int start = 0, sel = -1, firstv = -1;
#pragma unroll
        for (int w = 0; w < 4; ++w) {
            int cw = min(cnts[cc][w], NS_);
            if (firstv < 0 && cw > 0) firstv = cand[cc][(w << 6)];
            if (sel < 0 && k < start + cw) sel = cand[cc][(w << 6) + (k - start)];
            start += cw;
        }
        if (sel < 0) sel = firstv;
        gis[cc][k] = sel;
    }
    __syncthreads();

    if (t < 128) {
        int cc = t >> 6, k = t & 63;
        int gidx = gis[cc][k] & 8191;
        const float* P = pts + b * 3 * N_;
        float ccx = cc ? cx1 : cx0;
        float ccy = cc ? cy1 : cy0;
        float ccz = cc ? cz1 : cz0;
        f0[cc][k * 9 + 0] = X[gidx] - ccx;
        f0[cc][k * 9 + 1] = X[N_ + gidx] - ccy;
        f0[cc][k * 9 + 2] = X[2 * N_ + gidx] - ccz;
        f0[cc][k * 9 + 3] = P[gidx];
        f0[cc][k * 9 + 4] = P[N_ + gidx];
        f0[cc][k * 9 + 5] = P[2 * N_ + gidx];
    }
    __syncthreads();

    // (c) layer 0: 6 -> 64 on VALU; point = lane, wave owns 16-channel slice;
    // both centroids done by every thread (weights shared).
#pragma unroll 1
    for (int cc = 0; cc < 2; ++cc) {
        float in[6];
#pragma unroll
        for (int c = 0; c < 6; ++c) in[c] = f0[cc][lane * 9 + c];
#pragma unroll 1
        for (int i = 0; i < 16; i += 4) {
            int o = wq * 16 + i;
            float a0 = 0.f, a1 = 0.f, a2 = 0.f, a3 = 0.f;
#pragma unroll
            for (int c = 0; c < 6; ++c) {
                float rc = in[c];
                a0 = fmaf(rc, w0[(o + 0) * 6 + c], a0);
                a1 = fmaf(rc, w0[(o + 1) * 6 + c], a1);
                a2 = fmaf(rc, w0[(o + 2) * 6 + c], a2);
                a3 = fmaf(rc, w0[(o + 3) * 6 + c], a3);
            }
            feat[cc][lane * 72 + o + 0] = f2bf(fmaxf(fmaf(a0, scs[o + 0], ofs[o + 0]), 0.f));
            feat[cc][lane * 72 + o + 1] = f2bf(fmaxf(fmaf(a1, scs[o + 1], ofs[o + 1]), 0.f));
            feat[cc][lane * 72 + o + 2] = f2bf(fmaxf(fmaf(a2, scs[o + 2], ofs[o + 2]), 0.f));
            feat[cc][lane * 72 + o + 3] = f2bf(fmaxf(fmaf(a3, scs[o + 3], ofs[o + 3]), 0.f));
        }
    }
    __syncthreads();

    const int arow = 16 * wq + ln;   // this wave's m-tile row for A-frags
    const bool usebf = (wbf != nullptr);

    // layer 1: 64 -> 64 via MFMA (4 ntiles x 2 ksteps), weight frag feeds
    // both centroids' MFMAs. Reads precede in-place writes (same-wave DS
    // order; each wave owns its 16-row block in both phases).
    {
        bf16x8 a1f[2][2];
#pragma unroll
        for (int cc = 0; cc < 2; ++cc)
#pragma unroll
            for (int ks = 0; ks < 2; ++ks)
                a1f[cc][ks] = *(const bf16x8*)&feat[cc][arow * 72 + ks * 32 + quad * 8];

#pragma unroll
        for (int nt = 0; nt < 4; ++nt) {
            f32x4 acc0 = {0.f, 0.f, 0.f, 0.f};
            f32x4 acc1 = {0.f, 0.f, 0.f, 0.f};
#pragma unroll
            for (int ks = 0; ks < 2; ++ks) {
                int off = (nt * 16 + ln) * 64 + ks * 32 + quad * 8;
                bf16x8 bf;
                if (usebf) {
                    bf = *(const bf16x8*)&wbf[off];
                } else {
                    const float* wr = w1 + off;
                    float4 p = *(const float4*)wr;
                    float4 q = *(const float4*)(wr + 4);
                    bf = (bf16x8){f2bf(p.x), f2bf(p.y), f2bf(p.z), f2bf(p.w),
                                  f2bf(q.x), f2bf(q.y), f2bf(q.z), f2bf(q.w)};
                }
                acc0 = __builtin_amdgcn_mfma_f32_16x16x32_bf16(a1f[0][ks], bf, acc0, 0, 0, 0);
                acc1 = __builtin_amdgcn_mfma_f32_16x16x32_bf16(a1f[1][ks], bf, acc1, 0, 0, 0);
            }
            int o = nt * 16 + ln;
            float sc = scs[64 + o], of = ofs[64 + o];
#pragma unroll
            for (int reg = 0; reg < 4; ++reg) {
                float y0 = fmaxf(fmaf(acc0[reg], sc, of), 0.f);
                float y1 = fmaxf(fmaf(acc1[reg], sc, of), 0.f);
                feat[0][(16 * wq + quad * 4 + reg) * 72 + o] = f2bf(y0);
                feat[1][(16 * wq + quad * 4 + reg) * 72 + o] = f2bf(y1);
            }
        }
    }
    // no barrier: each wave reads back only its own m-tile rows

    // layer 2: 64 -> 128 via MFMA (8 ntiles x 2 ksteps) + fused k-max
    {
        bf16x8 a2f[2][2];
#pragma unroll
        for (int cc = 0; cc < 2; ++cc)
#pragma unroll
            for (int ks = 0; ks < 2; ++ks)
                a2f[cc][ks] = *(const bf16x8*)&feat[cc][arow * 72 + ks * 32 + quad * 8];

#pragma unroll
        for (int nt = 0; nt < 8; ++nt) {
            f32x4 acc0 = {0.f, 0.f, 0.f, 0.f};
            f32x4 acc1 = {0.f, 0.f, 0.f, 0.f};
#pragma unroll
            for (int ks = 0; ks < 2; ++ks) {
                int off = (nt * 16 + ln) * 64 + ks * 32 + quad * 8;
                bf16x8 bf;
                if (usebf) {
                    bf = *(const bf16x8*)&wbf[4096 + off];
                } else {
                    const float* wr = w2 + off;
                    float4 p = *(const float4*)wr;
                    float4 q = *(const float4*)(wr + 4);
                    bf = (bf16x8){f2bf(p.x), f2bf(p.y), f2bf(p.z), f2bf(p.w),
                                  f2bf(q.x), f2bf(q.y), f2bf(q.z), f2bf(q.w)};
                }
                acc0 = __builtin_amdgcn_mfma_f32_16x16x32_bf16(a2f[0][ks], bf, acc0, 0, 0, 0);
                acc1 = __builtin_amdgcn_mfma_f32_16x16x32_bf16(a2f[1][ks], bf, acc1, 0, 0, 0);
            }
            int o = nt * 16 + ln;
            float sc = scs[128 + o], of = ofs[128 + o];
            float m0_ = -1.f, m1_ = -1.f;
#pragma unroll
            for (int reg = 0; reg < 4; ++reg) {
                m0_ = fmaxf(m0_, fmaxf(fmaf(acc0[reg], sc, of), 0.f));
                m1_ = fmaxf(m1_, fmaxf(fmaf(acc1[reg], sc, of), 0.f));
            }
            m0_ = fmaxf(m0_, __shfl_xor(m0_, 16, 64));
            m0_ = fmaxf(m0_, __shfl_xor(m0_, 32, 64));
            m1_ = fmaxf(m1_, __shfl_xor(m1_, 16, 64));
            m1_ = fmaxf(m1_, __shfl_xor(m1_, 32, 64));
            if (lane < 16) {
                wmaxs[0][wq * 132 + o] = m0_;
                wmaxs[1][wq * 132 + o] = m1_;
            }
        }
    }
    __syncthreads();

    // final: max over the 4 waves' m-tiles, store new_points for both
    {
        int cc = t >> 7, ch = t & 127;
        float m = fmaxf(fmaxf(wmaxs[cc][0 * 132 + ch], wmaxs[cc][1 * 132 + ch]),
                        fmaxf(wmaxs[cc][2 * 132 + ch], wmaxs[cc][3 * 132 + ch]));
        out[OUT1 + (b * 128 + ch) * S_ + s0 + cc] = m;
    }
}

extern "C" void kernel_launch(void* const* d_in, const int* in_sizes, int n_in,
                              void* d_out, int out_size, void* d_ws, size_t ws_size,
                              hipStream_t stream) {
    const float* xyz  = (const float*)d_in[0];
    const float* pts  = (const float*)d_in[1];
    const int*   seed = (const int*)d_in[2];
    const float* w0 = (const float*)d_in[3];
    const float* b0 = (const float*)d_in[4];
    const float* g0 = (const float*)d_in[5];
    const float* be0 = (const float*)d_in[6];
    const float* m0 = (const float*)d_in[7];
    const float* v0 = (const float*)d_in[8];
    const float* w1 = (const float*)d_in[9];
    const float* b1 = (const float*)d_in[10];
    const float* g1 = (const float*)d_in[11];
    const float* be1 = (const float*)d_in[12];
    const float* m1 = (const float*)d_in[13];
    const float* v1 = (const float*)d_in[14];
    const float* w2 = (const float*)d_in[15];
    const float* b2 = (const float*)d_in[16];
    const float* g2 = (const float*)d_in[17];
    const float* be2 = (const float*)d_in[18];
    const float* m2 = (const float*)d_in[19];
    const float* v2 = (const float*)d_in[20];
    float* out = (float*)d_out;

    short* wbf = nullptr;
    if (ws_size >= 12288 * sizeof(short)) {
        wbf = (short*)d_ws;
        wconv_kernel<<<dim3(48), dim3(256), 0, stream>>>(w1, w2, wbf);
    }

    fps_kernel<<<dim3(B_), dim3(FPS_T), 0, stream>>>(xyz, out);
    down_kernel<<<dim3(B_ * S_ / 2), dim3(256), 0, stream>>>(xyz, pts, seed,
        w0, b0, g0, be0, m0, v0,
        w1, b1, g1, be1, m1, v1,
        w2, b2, g2, be2, m2, v2,
        out, wbf);
}